// Round 3
// baseline (380.792 us; speedup 1.0000x reference)
//
#include <hip/hip_runtime.h>

// ---------------- problem constants ----------------
#define N0 262144
#define N1 32768
#define N2 4096
#define EPSBN 1e-5f

typedef unsigned short ush_t;
typedef __bf16 bf16x8 __attribute__((ext_vector_type(8)));
typedef float  f32x4  __attribute__((ext_vector_type(4)));

union ufcast { unsigned int u; float f; };
__device__ __forceinline__ float bflo(unsigned int p) { ufcast x; x.u = p << 16;          return x.f; }
__device__ __forceinline__ float bfhi(unsigned int p) { ufcast x; x.u = p & 0xffff0000u; return x.f; }
__device__ __forceinline__ ush_t f2bf(float f) {
    ufcast x; x.f = f;
    unsigned int u = x.u + 0x7fffu + ((x.u >> 16) & 1u);
    return (ush_t)(u >> 16);
}
__device__ __forceinline__ bf16x8 as_bf8(uint4 u) {
    union { uint4 u; bf16x8 b; } x; x.u = u; return x.b;
}

// ss computation from NB bins (no fences: bins complete at kernel boundary).
// C = channel count of the normalized tensor. bins layout [NB][2C].
template<int C, int NB>
__device__ __forceinline__ void compute_ss(const float* __restrict__ bins,
                                           const float* __restrict__ g, const float* __restrict__ b,
                                           float M, float* ssl)
{
    const int tid = threadIdx.x;
    if (tid < 2 * C) {
        float s = 0.f;
#pragma unroll
        for (int k = 0; k < NB; ++k) s += bins[k * 2 * C + tid];
        ssl[tid] = s;
    }
    __syncthreads();
    if (tid < C) {
        const float mu  = ssl[tid] / M;
        const float var = fmaxf(ssl[C + tid] / M - mu * mu, 0.f);
        const float sc  = g[tid] / sqrtf(var + EPSBN);
        const float sh  = b[tid] - mu * sc;
        ssl[tid] = sc; ssl[C + tid] = sh;
    }
    __syncthreads();
}

// ---------------- prep: all weights + input pack + bins zero in one dispatch ----------------
template<int K, int CIN, int CINP_W, int COUT, int COUTP, int NCH>
__device__ __forceinline__ void prep_stage(const float* __restrict__ W, ush_t* __restrict__ Wb, int e) {
    const int k  = e & 31;
    const int n  = (e >> 5) % COUTP;
    const int ch = e / (32 * COUTP);
    const int kp = ch * 32 + k;
    const int t  = kp / CINP_W;
    const int c  = kp % CINP_W;
    float v = 0.f;
    if (t < K && c < CIN && n < COUT) v = W[((size_t)t * CIN + c) * COUT + n];
    Wb[e] = f2bf(v);
}

#define BINS_TOTAL 21504   // 64*48 + 64*96 + 64*96 + 16*192 + 16*192

__global__ __launch_bounds__(256) void prep_all(
    const float* w0, const float* wd0, const float* w1, const float* wd1, const float* wp,
    const float* data,
    ush_t* wbA, ush_t* wbB, ush_t* wbC, ush_t* wbD, ush_t* wbE, ush_t* xa, float* binsz)
{
    const int e = blockIdx.x * 256 + threadIdx.x;
    switch (blockIdx.y) {
        case 0: if (e <   4096) prep_stage<27,  3,  4, 24, 32,  4>(w0,  wbA, e); break;
        case 1: if (e <  12288) prep_stage< 8, 24, 32, 48, 48,  8>(wd0, wbB, e); break;
        case 2: if (e <  64512) prep_stage<27, 48, 48, 48, 48, 42>(w1,  wbC, e); break;  // flattened-dense K
        case 3: if (e <  49152) prep_stage< 8, 48, 64, 96, 96, 16>(wd1, wbD, e); break;
        case 4: if (e < 248832) prep_stage<27, 96, 96, 96, 96, 81>(wp,  wbE, e); break;
        case 5: if (e < N0) {
            const float* dp = data + (size_t)3 * e;
            unsigned int h0 = f2bf(dp[0]), h1 = f2bf(dp[1]), h2 = f2bf(dp[2]);
            uint2 v; v.x = h0 | (h1 << 16); v.y = h2;
            ((uint2*)xa)[e] = v;
        } break;
        case 6: if (e < BINS_TOTAL) binsz[e] = 0.f; break;
    }
}

// ---------------- stage A: 128 rows/block, 2 row-groups per wave (2x MLP) ----------------
__global__ __launch_bounds__(256) void mconvA_s(
    const ush_t* __restrict__ xa,     // [N0,4] bf16
    const int*   __restrict__ neigh,  // [N0,27]
    const ush_t* __restrict__ Wb,     // [4][32][32] bf16
    ush_t*       __restrict__ y,      // [N0,24] bf16 (pre-BN)
    float*       __restrict__ bins)   // [64][48]
{
    __shared__ int   nl[3456];        // 128 rows x 27 taps
    __shared__ float lsq[48];
    __shared__ ush_t ytile[128 * 24];
    const int tid = threadIdx.x;
    const int block0 = blockIdx.x * 128;

    {   // 864 uint4 loads for the neigh slab
        const uint4* src = (const uint4*)(neigh + (size_t)block0 * 27);
        uint4* dst = (uint4*)nl;
        for (int i = tid; i < 864; i += 256) dst[i] = src[i];
    }
    if (tid < 48) lsq[tid] = 0.f;
    __syncthreads();

    const int lane = tid & 63, wave = tid >> 6;
    const int quad = lane >> 4, l15 = lane & 15;

    f32x4 acc[2][2] = {};
#pragma unroll
    for (int g = 0; g < 2; ++g) {
        const int lr = g * 64 + wave * 16 + l15;
#pragma unroll
        for (int ch = 0; ch < 4; ++ch) {
            const int tA = ch * 8 + quad * 2;
            uint4 au = make_uint4(0, 0, 0, 0);
            if (ch < 3) {
                const uint2 lo = ((const uint2*)xa)[nl[lr * 27 + tA]];
                const uint2 hi = ((const uint2*)xa)[nl[lr * 27 + tA + 1]];
                au = make_uint4(lo.x, lo.y, hi.x, hi.y);
            } else {
                if (quad == 0) {
                    const uint2 lo = ((const uint2*)xa)[nl[lr * 27 + 24]];
                    const uint2 hi = ((const uint2*)xa)[nl[lr * 27 + 25]];
                    au = make_uint4(lo.x, lo.y, hi.x, hi.y);
                } else if (quad == 1) {
                    const uint2 lo = ((const uint2*)xa)[nl[lr * 27 + 26]];
                    au = make_uint4(lo.x, lo.y, 0, 0);
                }
            }
            const bf16x8 af = as_bf8(au);
#pragma unroll
            for (int ct = 0; ct < 2; ++ct) {
                const int n = ct * 16 + l15;
                const uint4 bu = *(const uint4*)(Wb + ((size_t)ch * 32 + n) * 32 + quad * 8);
                acc[g][ct] = __builtin_amdgcn_mfma_f32_16x16x32_bf16(af, as_bf8(bu), acc[g][ct], 0, 0, 0);
            }
        }
    }

#pragma unroll
    for (int g = 0; g < 2; ++g)
#pragma unroll
    for (int ct = 0; ct < 2; ++ct) {
        const int col = ct * 16 + l15;
        if (col < 24) {
            float s = 0.f, q = 0.f;
#pragma unroll
            for (int r = 0; r < 4; ++r) {
                const float v = acc[g][ct][r];
                ytile[(g * 64 + wave * 16 + quad * 4 + r) * 24 + col] = f2bf(v);
                s += v; q += v * v;
            }
            atomicAdd(&lsq[col], s);
            atomicAdd(&lsq[24 + col], q);
        }
    }
    __syncthreads();

    {   // coalesced flush: 384 uint4 (128*24 bf16)
        const uint4* t4 = (const uint4*)ytile;
        uint4* dst = (uint4*)(y + (size_t)block0 * 24);
        for (int i = tid; i < 384; i += 256) dst[i] = t4[i];
    }
    if (tid < 48) atomicAdd(&bins[(blockIdx.x & 63) * 48 + tid], lsq[tid]);
}

// ---------------- stage B: 16-row blocks (2048), wave-split ci, LDS tile reduce ----------------
__global__ __launch_bounds__(256) void mconvB_s(
    const ush_t* __restrict__ y0,     // [N0,24] bf16 pre-BN
    const float* __restrict__ bins0,  // [64][48]
    const float* __restrict__ g, const float* __restrict__ b,
    const int*   __restrict__ child,  // [N1,8]
    const ush_t* __restrict__ Wb,     // [8][48][32]
    ush_t*       __restrict__ y1b,    // [N1,48] bf16 (pre-BN)
    float*       __restrict__ bins1)  // [64][96]
{
    __shared__ float ssl[48];
    __shared__ float tile[16 * 48];
    const int tid = threadIdx.x;
    for (int i = tid; i < 768; i += 256) tile[i] = 0.f;
    compute_ss<24, 64>(bins0, g, b, (float)N0, ssl);

    const int lane = tid & 63, wave = tid >> 6;
    const int quad = lane >> 4, l15 = lane & 15;
    const int rowA = blockIdx.x * 16 + l15;
    const int c0 = quad * 8;

    float sc[8], sh[8];
    if (c0 < 24) {
#pragma unroll
        for (int j = 0; j < 8; ++j) { sc[j] = ssl[c0 + j]; sh[j] = ssl[24 + c0 + j]; }
    }

    // this wave's two child taps (8B contiguous)
    const int2 c2 = *(const int2*)(child + (size_t)rowA * 8 + wave * 2);

    f32x4 acc[3] = {};
#pragma unroll
    for (int u = 0; u < 2; ++u) {
        const int ci = wave * 2 + u;
        const int idx = u ? c2.y : c2.x;
        uint4 au = make_uint4(0, 0, 0, 0);
        if (c0 < 24) {
            const uint4 raw = *(const uint4*)(y0 + (size_t)idx * 24 + c0);
            const unsigned int w4[4] = {raw.x, raw.y, raw.z, raw.w};
            unsigned int o4[4];
#pragma unroll
            for (int h = 0; h < 4; ++h) {
                const float a0 = fmaxf(bflo(w4[h]) * sc[2 * h]     + sh[2 * h],     0.f);
                const float a1 = fmaxf(bfhi(w4[h]) * sc[2 * h + 1] + sh[2 * h + 1], 0.f);
                o4[h] = (unsigned)f2bf(a0) | ((unsigned)f2bf(a1) << 16);
            }
            au = make_uint4(o4[0], o4[1], o4[2], o4[3]);
        }
        const bf16x8 af = as_bf8(au);
#pragma unroll
        for (int ct = 0; ct < 3; ++ct) {
            const int n = ct * 16 + l15;
            const uint4 bu = *(const uint4*)(Wb + ((size_t)ci * 48 + n) * 32 + quad * 8);
            acc[ct] = __builtin_amdgcn_mfma_f32_16x16x32_bf16(af, as_bf8(bu), acc[ct], 0, 0, 0);
        }
    }

#pragma unroll
    for (int ct = 0; ct < 3; ++ct)
#pragma unroll
        for (int r = 0; r < 4; ++r)
            atomicAdd(&tile[(quad * 4 + r) * 48 + ct * 16 + l15], acc[ct][r]);
    __syncthreads();

    {   // flush 16x48 f32 -> bf16 pairs: 384 uint stores
        uint* dst = (uint*)(y1b + (size_t)blockIdx.x * 768);
        for (int i = tid; i < 384; i += 256)
            dst[i] = (unsigned)f2bf(tile[2 * i]) | ((unsigned)f2bf(tile[2 * i + 1]) << 16);
    }
    if (tid < 96) {
        const int c = (tid < 48) ? tid : tid - 48;
        float a = 0.f;
#pragma unroll
        for (int r = 0; r < 16; ++r) { const float v = tile[r * 48 + c]; a += (tid < 48) ? v : v * v; }
        atomicAdd(&bins1[(blockIdx.x & 63) * 96 + tid], a);
    }
}

// ---------------- stage C: 16-row blocks (2048), wave-split 42 chunks, LDS tile reduce ----------------
__global__ __launch_bounds__(256) void mconvC_s(
    const ush_t* __restrict__ y1b,    // [N1,48] bf16 pre-BN
    const float* __restrict__ bins1,  // [64][96]
    const float* __restrict__ g, const float* __restrict__ b,
    const int*   __restrict__ neigh,  // [N1,27]
    const ush_t* __restrict__ Wb,     // [42][48][32] (K rows g>=1296 zero)
    float*       __restrict__ y2,     // [N1,48]
    float*       __restrict__ bins2)  // [64][96]
{
    __shared__ float ssl[96];
    __shared__ int   nl[432];
    __shared__ float tile[16 * 48];
    const int tid = threadIdx.x;
    for (int i = tid; i < 768; i += 256) tile[i] = 0.f;

    {   // stage neigh slab: 108 uint4
        const uint4* src = (const uint4*)(neigh + (size_t)blockIdx.x * 432);
        uint4* dst = (uint4*)nl;
        for (int i = tid; i < 108; i += 256) dst[i] = src[i];
    }
    compute_ss<48, 64>(bins1, g, b, (float)N1, ssl);   // final sync covers nl + tile init

    const int lane = tid & 63, wave = tid >> 6;
    const int quad = lane >> 4, l15 = lane & 15;

    int coffs[3], tofs[3];
    float sc[3][8], sh[3][8];
#pragma unroll
    for (int m3 = 0; m3 < 3; ++m3) {
        const int gg = 32 * m3 + 8 * quad;
        coffs[m3] = gg % 48;
        tofs[m3]  = gg / 48;
#pragma unroll
        for (int j = 0; j < 8; ++j) { sc[m3][j] = ssl[coffs[m3] + j]; sh[m3][j] = ssl[48 + coffs[m3] + j]; }
    }

    f32x4 acc[3] = {};
    for (int ch = wave; ch < 42; ch += 4) {
        const int cg = ch / 3, m3 = ch - cg * 3;
        int t = 2 * cg + tofs[m3];
        if (t > 26) t = 26;                       // padded K rows have zero weights
        const int idx = nl[l15 * 27 + t];
        const uint4 raw = *(const uint4*)(y1b + (size_t)idx * 48 + coffs[m3]);
        const unsigned int w4[4] = {raw.x, raw.y, raw.z, raw.w};
        unsigned int o4[4];
#pragma unroll
        for (int h = 0; h < 4; ++h) {
            const float a0 = fmaxf(bflo(w4[h]) * sc[m3][2 * h]     + sh[m3][2 * h],     0.f);
            const float a1 = fmaxf(bfhi(w4[h]) * sc[m3][2 * h + 1] + sh[m3][2 * h + 1], 0.f);
            o4[h] = (unsigned)f2bf(a0) | ((unsigned)f2bf(a1) << 16);
        }
        const bf16x8 af = as_bf8(make_uint4(o4[0], o4[1], o4[2], o4[3]));
#pragma unroll
        for (int ct = 0; ct < 3; ++ct) {
            const int n = ct * 16 + l15;
            const uint4 bu = *(const uint4*)(Wb + ((size_t)ch * 48 + n) * 32 + quad * 8);
            acc[ct] = __builtin_amdgcn_mfma_f32_16x16x32_bf16(af, as_bf8(bu), acc[ct], 0, 0, 0);
        }
    }

#pragma unroll
    for (int ct = 0; ct < 3; ++ct)
#pragma unroll
        for (int r = 0; r < 4; ++r)
            atomicAdd(&tile[(quad * 4 + r) * 48 + ct * 16 + l15], acc[ct][r]);
    __syncthreads();

    {   // flush 16x48 f32: 192 uint4
        const uint4* t4 = (const uint4*)tile;
        uint4* dst = (uint4*)(y2 + (size_t)blockIdx.x * 768);
        for (int i = tid; i < 192; i += 256) dst[i] = t4[i];
    }
    if (tid < 96) {
        const int c = (tid < 48) ? tid : tid - 48;
        float a = 0.f;
#pragma unroll
        for (int r = 0; r < 16; ++r) { const float v = tile[r * 48 + c]; a += (tid < 48) ? v : v * v; }
        atomicAdd(&bins2[(blockIdx.x & 63) * 96 + tid], a);
    }
}

// ---------------- stage D: 1024 threads, 16 waves (one ci each), LDS-tile reduce ----------------
__global__ __launch_bounds__(1024) void mconvD_s(
    const float* __restrict__ y2, const float* __restrict__ bins2,  // bins2: [64][96] (48-ch moments)
    const float* __restrict__ g, const float* __restrict__ b,
    const int*   __restrict__ child,  // [N2,8]
    const ush_t* __restrict__ Wb,     // [16][96][32]
    float*       __restrict__ y3,     // [N2,96]
    float*       __restrict__ bins3)  // [16][192]
{
    __shared__ float ssl[96];
    __shared__ float tile[16 * 96];
    __shared__ int   cl[128];
    const int tid = threadIdx.x;
    for (int i = tid; i < 1536; i += 1024) tile[i] = 0.f;
    {   // stage child slab: 32 uint4
        const uint4* src = (const uint4*)(child + (size_t)blockIdx.x * 128);
        uint4* dst = (uint4*)cl;
        if (tid < 32) dst[tid] = src[tid];
    }
    compute_ss<48, 64>(bins2, g, b, (float)N1, ssl);   // final sync covers tile + cl

    const int lane = tid & 63, wave = tid >> 6;
    const int quad = lane >> 4, l15 = lane & 15;

    const int ci = wave;
    const int t = ci >> 1, sub = ci & 1;
    const int idx = cl[l15 * 8 + t];
    const int c0 = sub * 32 + quad * 8;

    f32x4 acc[6] = {};
    {
        uint4 au = make_uint4(0, 0, 0, 0);
        if (c0 < 48) {
            const float4 v0 = *(const float4*)(y2 + (size_t)idx * 48 + c0);
            const float4 v1 = *(const float4*)(y2 + (size_t)idx * 48 + c0 + 4);
            const float vv[8] = {v0.x, v0.y, v0.z, v0.w, v1.x, v1.y, v1.z, v1.w};
            unsigned int o4[4];
#pragma unroll
            for (int h = 0; h < 4; ++h) {
                const float a0 = fmaxf(vv[2 * h]     * ssl[c0 + 2 * h]     + ssl[48 + c0 + 2 * h],     0.f);
                const float a1 = fmaxf(vv[2 * h + 1] * ssl[c0 + 2 * h + 1] + ssl[48 + c0 + 2 * h + 1], 0.f);
                o4[h] = (unsigned)f2bf(a0) | ((unsigned)f2bf(a1) << 16);
            }
            au = make_uint4(o4[0], o4[1], o4[2], o4[3]);
        }
        const bf16x8 af = as_bf8(au);
#pragma unroll
        for (int ct = 0; ct < 6; ++ct) {
            const int n = ct * 16 + l15;
            const uint4 bu = *(const uint4*)(Wb + ((size_t)ci * 96 + n) * 32 + quad * 8);
            acc[ct] = __builtin_amdgcn_mfma_f32_16x16x32_bf16(af, as_bf8(bu), acc[ct], 0, 0, 0);
        }
    }

#pragma unroll
    for (int ct = 0; ct < 6; ++ct)
#pragma unroll
        for (int r = 0; r < 4; ++r)
            atomicAdd(&tile[(quad * 4 + r) * 96 + ct * 16 + l15], acc[ct][r]);
    __syncthreads();

    const size_t row0 = (size_t)blockIdx.x * 16;
    for (int i = tid; i < 1536; i += 1024) y3[row0 * 96 + i] = tile[i];
    if (tid < 192) {
        const int c = (tid < 96) ? tid : tid - 96;
        float a = 0.f;
#pragma unroll
        for (int r = 0; r < 16; ++r) { const float v = tile[r * 96 + c]; a += (tid < 96) ? v : v * v; }
        atomicAdd(&bins3[(blockIdx.x & 15) * 192 + tid], a);
    }
}

// ---------------- stage E: 1024 threads, 16 waves split 81 chunks (6/5...), LDS-tile reduce ----------------
__global__ __launch_bounds__(1024) void mconvE_s(
    const float* __restrict__ y3, const float* __restrict__ bins3,  // bins3: [16][192] (96-ch moments)
    const float* __restrict__ g, const float* __restrict__ b,
    const int*   __restrict__ neigh,  // [N2,27]
    const ush_t* __restrict__ Wb,     // [81][96][32]
    float*       __restrict__ y4,     // [N2,96]
    float*       __restrict__ bins4)  // [16][192]
{
    __shared__ float ssl[192];
    __shared__ float tile[16 * 96];
    __shared__ int   nl[432];
    const int tid = threadIdx.x;
    for (int i = tid; i < 1536; i += 1024) tile[i] = 0.f;

    {   // stage neigh slab: 108 uint4
        const uint4* src = (const uint4*)(neigh + (size_t)blockIdx.x * 432);
        uint4* dst = (uint4*)nl;
        if (tid < 108) dst[tid] = src[tid];
    }
    compute_ss<96, 16>(bins3, g, b, (float)N2, ssl);   // final sync covers tile + nl

    const int lane = tid & 63, wave = tid >> 6;
    const int quad = lane >> 4, l15 = lane & 15;

    const int cnt = (wave == 0) ? 6 : 5;   // chunks: wave, wave+16, ... (<81)

    f32x4 acc[6] = {};
    for (int u = 0; u < cnt; ++u) {
        const int ci = wave + 16 * u;
        const int t = ci / 3, sub = ci - t * 3;
        const int idx = nl[l15 * 27 + t];
        const int c0 = sub * 32 + quad * 8;
        const float4 v0 = *(const float4*)(y3 + (size_t)idx * 96 + c0);
        const float4 v1 = *(const float4*)(y3 + (size_t)idx * 96 + c0 + 4);
        const float vv[8] = {v0.x, v0.y, v0.z, v0.w, v1.x, v1.y, v1.z, v1.w};
        unsigned int o4[4];
#pragma unroll
        for (int h = 0; h < 4; ++h) {
            const float a0 = fmaxf(vv[2 * h]     * ssl[c0 + 2 * h]     + ssl[96 + c0 + 2 * h],     0.f);
            const float a1 = fmaxf(vv[2 * h + 1] * ssl[c0 + 2 * h + 1] + ssl[96 + c0 + 2 * h + 1], 0.f);
            o4[h] = (unsigned)f2bf(a0) | ((unsigned)f2bf(a1) << 16);
        }
        const bf16x8 af = as_bf8(make_uint4(o4[0], o4[1], o4[2], o4[3]));
#pragma unroll
        for (int ct = 0; ct < 6; ++ct) {
            const int n = ct * 16 + l15;
            const uint4 bu = *(const uint4*)(Wb + ((size_t)ci * 96 + n) * 32 + quad * 8);
            acc[ct] = __builtin_amdgcn_mfma_f32_16x16x32_bf16(af, as_bf8(bu), acc[ct], 0, 0, 0);
        }
    }

#pragma unroll
    for (int ct = 0; ct < 6; ++ct)
#pragma unroll
        for (int r = 0; r < 4; ++r)
            atomicAdd(&tile[(quad * 4 + r) * 96 + ct * 16 + l15], acc[ct][r]);
    __syncthreads();

    const size_t row0 = (size_t)blockIdx.x * 16;
    for (int i = tid; i < 1536; i += 1024) y4[row0 * 96 + i] = tile[i];
    if (tid < 192) {
        const int c = (tid < 96) ? tid : tid - 96;
        float a = 0.f;
#pragma unroll
        for (int r = 0; r < 16; ++r) { const float v = tile[r * 96 + c]; a += (tid < 96) ? v : v * v; }
        atomicAdd(&bins4[(blockIdx.x & 15) * 192 + tid], a);
    }
}

// ---------------- final write: ss4 in-kernel ----------------
__global__ __launch_bounds__(256) void writeout_s(
    const float* __restrict__ y4, const float* __restrict__ bins4,
    const float* __restrict__ g, const float* __restrict__ b,
    float* __restrict__ out)
{
    __shared__ float ssl[192];
    compute_ss<96, 16>(bins4, g, b, (float)N2, ssl);

    const int i = (blockIdx.x * 256 + threadIdx.x) * 4;   // over N2*96
    const int c = i % 96;
    float4 v = *(const float4*)(y4 + i);
    float4 o;
    o.x = fmaxf(v.x * ssl[c + 0] + ssl[96 + c + 0], 0.f);
    o.y = fmaxf(v.y * ssl[c + 1] + ssl[96 + c + 1], 0.f);
    o.z = fmaxf(v.z * ssl[c + 2] + ssl[96 + c + 2], 0.f);
    o.w = fmaxf(v.w * ssl[c + 3] + ssl[96 + c + 3], 0.f);
    *(float4*)(out + i) = o;
}

// ---------------- host ----------------
extern "C" void kernel_launch(void* const* d_in, const int* in_sizes, int n_in,
                              void* d_out, int out_size, void* d_ws, size_t ws_size,
                              hipStream_t stream)
{
    const float* data   = (const float*)d_in[0];
    const int*   neigh0 = (const int*)d_in[1];
    const int*   child0 = (const int*)d_in[2];
    const int*   neigh1 = (const int*)d_in[3];
    const int*   child1 = (const int*)d_in[4];
    const int*   neigh2 = (const int*)d_in[5];
    const float* w0  = (const float*)d_in[6];
    const float* g0  = (const float*)d_in[7];
    const float* b0  = (const float*)d_in[8];
    const float* wd0 = (const float*)d_in[9];
    const float* gd0 = (const float*)d_in[10];
    const float* bd0 = (const float*)d_in[11];
    const float* w1  = (const float*)d_in[12];
    const float* g1  = (const float*)d_in[13];
    const float* b1  = (const float*)d_in[14];
    const float* wd1 = (const float*)d_in[15];
    const float* gd1 = (const float*)d_in[16];
    const float* bd1 = (const float*)d_in[17];
    const float* wp  = (const float*)d_in[18];
    const float* gp  = (const float*)d_in[19];
    const float* bp  = (const float*)d_in[20];
    float* out = (float*)d_out;

    // bins header (floats) — zeroed by prep_all case 6
    float* wsf = (float*)d_ws;
    float* bins0 = wsf;            // 64*48  = 3072
    float* bins1 = wsf + 3072;     // 64*96  = 6144
    float* bins2 = wsf + 9216;     // 6144
    float* bins3 = wsf + 15360;    // 16*192 = 3072
    float* bins4 = wsf + 18432;    // 3072 -> 21504 total

    // arena
    float* Y2  = wsf + 21504;                        // N1*48 = 1,572,864 f
    float* Y3  = Y2 + (size_t)1572864;               // N2*96 =   393,216 f
    float* Y4  = Y3 + (size_t)393216;                //   393,216 f
    ush_t* Y0B = (ush_t*)(Y4 + (size_t)393216);      // 6,291,456 ush: y0 bf16 [N0,24]
    ush_t* Y1B = Y0B + (size_t)6291456;              // 1,572,864 ush: y1 bf16 [N1,48]
    ush_t* XA  = Y1B + (size_t)1572864;              // 1,048,576 ush: packed input [N0,4]
    ush_t* WB  = XA + (size_t)1048576;               //   524,288 ush: prepped weights

    ush_t* wbA = WB;                 //   4,096
    ush_t* wbB = WB + 4096;          //  12,288
    ush_t* wbC = WB + 16384;         //  64,512 (flattened 42 chunks)
    ush_t* wbD = WB + 80896;         //  49,152
    ush_t* wbE = WB + 130048;        // 248,832 -> end 378,880

    prep_all<<<dim3(1024, 7), 256, 0, stream>>>(w0, wd0, w1, wd1, wp, data,
                                                wbA, wbB, wbC, wbD, wbE, XA, wsf);

    mconvA_s<<<N0 / 128, 256, 0, stream>>>(XA, neigh0, wbA, Y0B, bins0);
    mconvB_s<<<N1 / 16, 256, 0, stream>>>(Y0B, bins0, g0, b0, child0, wbB, Y1B, bins1);
    mconvC_s<<<N1 / 16, 256, 0, stream>>>(Y1B, bins1, gd0, bd0, neigh1, wbC, Y2, bins2);
    mconvD_s<<<N2 / 16, 1024, 0, stream>>>(Y2, bins2, g1, b1, child1, wbD, Y3, bins3);
    mconvE_s<<<N2 / 16, 1024, 0, stream>>>(Y3, bins3, gd1, bd1, neigh2, wbE, Y4, bins4);
    writeout_s<<<N2 * 96 / 4 / 256, 256, 0, stream>>>(Y4, bins4, gp, bp, out);

    (void)in_sizes; (void)n_in; (void)out_size; (void)ws_size;
}

// Round 4
// 234.600 us; speedup vs baseline: 1.6232x; 1.6232x over previous
//
#include <hip/hip_runtime.h>

// ---------------- problem constants ----------------
#define N0 262144
#define N1 32768
#define N2 4096
#define EPSBN 1e-5f

typedef unsigned short ush_t;
typedef __bf16 bf16x8 __attribute__((ext_vector_type(8)));
typedef float  f32x4  __attribute__((ext_vector_type(4)));

union ufcast { unsigned int u; float f; };
__device__ __forceinline__ float bflo(unsigned int p) { ufcast x; x.u = p << 16;          return x.f; }
__device__ __forceinline__ float bfhi(unsigned int p) { ufcast x; x.u = p & 0xffff0000u; return x.f; }
__device__ __forceinline__ ush_t f2bf(float f) {
    ufcast x; x.f = f;
    unsigned int u = x.u + 0x7fffu + ((x.u >> 16) & 1u);
    return (ush_t)(u >> 16);
}
__device__ __forceinline__ bf16x8 as_bf8(uint4 u) {
    union { uint4 u; bf16x8 b; } x; x.u = u; return x.b;
}

// ss computation from NB bins (no fences: bins complete at kernel boundary).
// C = channel count of the normalized tensor. bins layout [NB][2C].
template<int C, int NB>
__device__ __forceinline__ void compute_ss(const float* __restrict__ bins,
                                           const float* __restrict__ g, const float* __restrict__ b,
                                           float M, float* ssl)
{
    const int tid = threadIdx.x;
    if (tid < 2 * C) {
        float s = 0.f;
#pragma unroll
        for (int k = 0; k < NB; ++k) s += bins[k * 2 * C + tid];
        ssl[tid] = s;
    }
    __syncthreads();
    if (tid < C) {
        const float mu  = ssl[tid] / M;
        const float var = fmaxf(ssl[C + tid] / M - mu * mu, 0.f);
        const float sc  = g[tid] / sqrtf(var + EPSBN);
        const float sh  = b[tid] - mu * sc;
        ssl[tid] = sc; ssl[C + tid] = sh;
    }
    __syncthreads();
}

// ---------------- prep: all weights + input pack + bins zero in one dispatch ----------------
template<int K, int CIN, int CINP_W, int COUT, int COUTP, int NCH>
__device__ __forceinline__ void prep_stage(const float* __restrict__ W, ush_t* __restrict__ Wb, int e) {
    const int k  = e & 31;
    const int n  = (e >> 5) % COUTP;
    const int ch = e / (32 * COUTP);
    const int kp = ch * 32 + k;
    const int t  = kp / CINP_W;
    const int c  = kp % CINP_W;
    float v = 0.f;
    if (t < K && c < CIN && n < COUT) v = W[((size_t)t * CIN + c) * COUT + n];
    Wb[e] = f2bf(v);
}

#define BINS_TOTAL 9984   // 16*48 + 16*96 + 16*96 + 16*192 + 16*192

__global__ __launch_bounds__(256) void prep_all(
    const float* w0, const float* wd0, const float* w1, const float* wd1, const float* wp,
    const float* data,
    ush_t* wbA, ush_t* wbB, ush_t* wbC, ush_t* wbD, ush_t* wbE, ush_t* xa, float* binsz)
{
    const int e = blockIdx.x * 256 + threadIdx.x;
    switch (blockIdx.y) {
        case 0: if (e <   4096) prep_stage<27,  3,  4, 24, 32,  4>(w0,  wbA, e); break;
        case 1: if (e <  12288) prep_stage< 8, 24, 32, 48, 48,  8>(wd0, wbB, e); break;
        case 2: if (e <  64512) prep_stage<27, 48, 48, 48, 48, 42>(w1,  wbC, e); break;  // flattened-dense K
        case 3: if (e <  49152) prep_stage< 8, 48, 64, 96, 96, 16>(wd1, wbD, e); break;
        case 4: if (e < 248832) prep_stage<27, 96, 96, 96, 96, 81>(wp,  wbE, e); break;
        case 5: if (e < N0) {
            const float* dp = data + (size_t)3 * e;
            unsigned int h0 = f2bf(dp[0]), h1 = f2bf(dp[1]), h2 = f2bf(dp[2]);
            uint2 v; v.x = h0 | (h1 << 16); v.y = h2;
            ((uint2*)xa)[e] = v;
        } break;
        case 6: if (e < BINS_TOTAL) binsz[e] = 0.f; break;
    }
}

// ---------------- stage A: 128 rows/block, 2 row-groups per wave (2x MLP) ----------------
__global__ __launch_bounds__(256) void mconvA_s(
    const ush_t* __restrict__ xa,     // [N0,4] bf16
    const int*   __restrict__ neigh,  // [N0,27]
    const ush_t* __restrict__ Wb,     // [4][32][32] bf16
    ush_t*       __restrict__ y,      // [N0,24] bf16 (pre-BN)
    float*       __restrict__ bins)   // [16][48]
{
    __shared__ int   nl[3456];        // 128 rows x 27 taps
    __shared__ float lsq[48];
    __shared__ ush_t ytile[128 * 24];
    const int tid = threadIdx.x;
    const int block0 = blockIdx.x * 128;

    {   // 864 uint4 loads for the neigh slab
        const uint4* src = (const uint4*)(neigh + (size_t)block0 * 27);
        uint4* dst = (uint4*)nl;
        for (int i = tid; i < 864; i += 256) dst[i] = src[i];
    }
    if (tid < 48) lsq[tid] = 0.f;
    __syncthreads();

    const int lane = tid & 63, wave = tid >> 6;
    const int quad = lane >> 4, l15 = lane & 15;

    f32x4 acc[2][2] = {};
#pragma unroll
    for (int g = 0; g < 2; ++g) {
        const int lr = g * 64 + wave * 16 + l15;
#pragma unroll
        for (int ch = 0; ch < 4; ++ch) {
            const int tA = ch * 8 + quad * 2;
            uint4 au = make_uint4(0, 0, 0, 0);
            if (ch < 3) {
                const uint2 lo = ((const uint2*)xa)[nl[lr * 27 + tA]];
                const uint2 hi = ((const uint2*)xa)[nl[lr * 27 + tA + 1]];
                au = make_uint4(lo.x, lo.y, hi.x, hi.y);
            } else {
                if (quad == 0) {
                    const uint2 lo = ((const uint2*)xa)[nl[lr * 27 + 24]];
                    const uint2 hi = ((const uint2*)xa)[nl[lr * 27 + 25]];
                    au = make_uint4(lo.x, lo.y, hi.x, hi.y);
                } else if (quad == 1) {
                    const uint2 lo = ((const uint2*)xa)[nl[lr * 27 + 26]];
                    au = make_uint4(lo.x, lo.y, 0, 0);
                }
            }
            const bf16x8 af = as_bf8(au);
#pragma unroll
            for (int ct = 0; ct < 2; ++ct) {
                const int n = ct * 16 + l15;
                const uint4 bu = *(const uint4*)(Wb + ((size_t)ch * 32 + n) * 32 + quad * 8);
                acc[g][ct] = __builtin_amdgcn_mfma_f32_16x16x32_bf16(af, as_bf8(bu), acc[g][ct], 0, 0, 0);
            }
        }
    }

#pragma unroll
    for (int g = 0; g < 2; ++g)
#pragma unroll
    for (int ct = 0; ct < 2; ++ct) {
        const int col = ct * 16 + l15;
        if (col < 24) {
            float s = 0.f, q = 0.f;
#pragma unroll
            for (int r = 0; r < 4; ++r) {
                const float v = acc[g][ct][r];
                ytile[(g * 64 + wave * 16 + quad * 4 + r) * 24 + col] = f2bf(v);
                s += v; q += v * v;
            }
            atomicAdd(&lsq[col], s);
            atomicAdd(&lsq[24 + col], q);
        }
    }
    __syncthreads();

    {   // coalesced flush: 384 uint4 (128*24 bf16)
        const uint4* t4 = (const uint4*)ytile;
        uint4* dst = (uint4*)(y + (size_t)block0 * 24);
        for (int i = tid; i < 384; i += 256) dst[i] = t4[i];
    }
    if (tid < 48) atomicAdd(&bins[(blockIdx.x & 15) * 48 + tid], lsq[tid]);
}

// ---------------- stage B: vec child loads; LDS-tiled bf16 output ----------------
__global__ __launch_bounds__(256) void mconvB_s(
    const ush_t* __restrict__ y0,     // [N0,24] bf16 pre-BN
    const float* __restrict__ bins0,  // [16][48]
    const float* __restrict__ g, const float* __restrict__ b,
    const int*   __restrict__ child,  // [N1,8]
    const ush_t* __restrict__ Wb,     // [8][48][32]
    ush_t*       __restrict__ y1b,    // [N1,48] bf16 (pre-BN)
    float*       __restrict__ bins1)  // [16][96]
{
    __shared__ float ssl[48];
    __shared__ float lsq[96];
    __shared__ ush_t ytile[64 * 48];
    const int tid = threadIdx.x;
    if (tid < 96) lsq[tid] = 0.f;
    compute_ss<24, 16>(bins0, g, b, (float)N0, ssl);

    const int lane = tid & 63, wave = tid >> 6;
    const int quad = lane >> 4, l15 = lane & 15;
    const int rowA = blockIdx.x * 64 + wave * 16 + l15;
    const int c0 = quad * 8;

    float sc[8], sh[8];
    if (c0 < 24) {
#pragma unroll
        for (int j = 0; j < 8; ++j) { sc[j] = ssl[c0 + j]; sh[j] = ssl[24 + c0 + j]; }
    }

    // 2 vector loads instead of 8 scalar loads (32B contiguous per row)
    const int4 c4a = *(const int4*)(child + (size_t)rowA * 8);
    const int4 c4b = *(const int4*)(child + (size_t)rowA * 8 + 4);
    const int idxs[8] = {c4a.x, c4a.y, c4a.z, c4a.w, c4b.x, c4b.y, c4b.z, c4b.w};

    f32x4 acc[3] = {};
#pragma unroll
    for (int ci = 0; ci < 8; ++ci) {
        const int idx = idxs[ci];
        uint4 au = make_uint4(0, 0, 0, 0);
        if (c0 < 24) {
            const uint4 raw = *(const uint4*)(y0 + (size_t)idx * 24 + c0);
            const unsigned int w4[4] = {raw.x, raw.y, raw.z, raw.w};
            unsigned int o4[4];
#pragma unroll
            for (int h = 0; h < 4; ++h) {
                const float a0 = fmaxf(bflo(w4[h]) * sc[2 * h]     + sh[2 * h],     0.f);
                const float a1 = fmaxf(bfhi(w4[h]) * sc[2 * h + 1] + sh[2 * h + 1], 0.f);
                o4[h] = (unsigned)f2bf(a0) | ((unsigned)f2bf(a1) << 16);
            }
            au = make_uint4(o4[0], o4[1], o4[2], o4[3]);
        }
        const bf16x8 af = as_bf8(au);
#pragma unroll
        for (int ct = 0; ct < 3; ++ct) {
            const int n = ct * 16 + l15;
            const uint4 bu = *(const uint4*)(Wb + ((size_t)ci * 48 + n) * 32 + quad * 8);
            acc[ct] = __builtin_amdgcn_mfma_f32_16x16x32_bf16(af, as_bf8(bu), acc[ct], 0, 0, 0);
        }
    }

#pragma unroll
    for (int ct = 0; ct < 3; ++ct) {
        const int col = ct * 16 + l15;
        float s = 0.f, q = 0.f;
#pragma unroll
        for (int r = 0; r < 4; ++r) {
            const float v = acc[ct][r];
            ytile[(wave * 16 + quad * 4 + r) * 48 + col] = f2bf(v);
            s += v; q += v * v;
        }
        atomicAdd(&lsq[col], s);
        atomicAdd(&lsq[48 + col], q);
    }
    __syncthreads();

    {   // 384 uint4 flush
        const uint4* t4 = (const uint4*)ytile;
        uint4* dst = (uint4*)(y1b + (size_t)blockIdx.x * 64 * 48);
        for (int i = tid; i < 384; i += 256) dst[i] = t4[i];
    }
    if (tid < 96) atomicAdd(&bins1[(blockIdx.x & 15) * 96 + tid], lsq[tid]);
}

// ---------------- stage C: LDS neigh staging; flattened-dense K; LDS-tiled f32 output ----------------
__global__ __launch_bounds__(256) void mconvC_s(
    const ush_t* __restrict__ y1b,    // [N1,48] bf16 pre-BN
    const float* __restrict__ bins1,  // [16][96]
    const float* __restrict__ g, const float* __restrict__ b,
    const int*   __restrict__ neigh,  // [N1,27]
    const ush_t* __restrict__ Wb,     // [42][48][32] (K rows g>=1296 zero)
    float*       __restrict__ y2,     // [N1,48]
    float*       __restrict__ bins2)  // [16][96]
{
    __shared__ float ssl[96];
    __shared__ float lsq[96];
    __shared__ int   nl[1728];
    __shared__ float tile[64 * 48];
    const int tid = threadIdx.x;
    if (tid < 96) lsq[tid] = 0.f;

    {   // stage neigh slab: 432 uint4
        const uint4* src = (const uint4*)(neigh + (size_t)blockIdx.x * 1728);
        uint4* dst = (uint4*)nl;
        for (int i = tid; i < 432; i += 256) dst[i] = src[i];
    }
    compute_ss<48, 16>(bins1, g, b, (float)N1, ssl);   // final sync covers nl staging

    const int lane = tid & 63, wave = tid >> 6;
    const int quad = lane >> 4, l15 = lane & 15;
    const int rl = wave * 16 + l15;                // local row 0..63

    int coffs[3], tofs[3];
    float sc[3][8], sh[3][8];
#pragma unroll
    for (int m3 = 0; m3 < 3; ++m3) {
        const int gg = 32 * m3 + 8 * quad;
        coffs[m3] = gg % 48;
        tofs[m3]  = gg / 48;
#pragma unroll
        for (int j = 0; j < 8; ++j) { sc[m3][j] = ssl[coffs[m3] + j]; sh[m3][j] = ssl[48 + coffs[m3] + j]; }
    }

    f32x4 acc[3] = {};
    for (int cg = 0; cg < 14; ++cg) {
#pragma unroll
        for (int m3 = 0; m3 < 3; ++m3) {
            const int ch = 3 * cg + m3;
            int t = 2 * cg + tofs[m3];
            if (t > 26) t = 26;                       // padded K rows have zero weights
            const int idx = nl[rl * 27 + t];
            const uint4 raw = *(const uint4*)(y1b + (size_t)idx * 48 + coffs[m3]);
            const unsigned int w4[4] = {raw.x, raw.y, raw.z, raw.w};
            unsigned int o4[4];
#pragma unroll
            for (int h = 0; h < 4; ++h) {
                const float a0 = fmaxf(bflo(w4[h]) * sc[m3][2 * h]     + sh[m3][2 * h],     0.f);
                const float a1 = fmaxf(bfhi(w4[h]) * sc[m3][2 * h + 1] + sh[m3][2 * h + 1], 0.f);
                o4[h] = (unsigned)f2bf(a0) | ((unsigned)f2bf(a1) << 16);
            }
            const bf16x8 af = as_bf8(make_uint4(o4[0], o4[1], o4[2], o4[3]));
#pragma unroll
            for (int ct = 0; ct < 3; ++ct) {
                const int n = ct * 16 + l15;
                const uint4 bu = *(const uint4*)(Wb + ((size_t)ch * 48 + n) * 32 + quad * 8);
                acc[ct] = __builtin_amdgcn_mfma_f32_16x16x32_bf16(af, as_bf8(bu), acc[ct], 0, 0, 0);
            }
        }
    }

#pragma unroll
    for (int ct = 0; ct < 3; ++ct) {
        const int col = ct * 16 + l15;
        float s = 0.f, q = 0.f;
#pragma unroll
        for (int r = 0; r < 4; ++r) {
            const float v = acc[ct][r];
            tile[(wave * 16 + quad * 4 + r) * 48 + col] = v;
            s += v; q += v * v;
        }
        atomicAdd(&lsq[col], s);
        atomicAdd(&lsq[48 + col], q);
    }
    __syncthreads();

    {   // 768 uint4 flush
        const uint4* t4 = (const uint4*)tile;
        uint4* dst = (uint4*)(y2 + (size_t)blockIdx.x * 64 * 48);
        for (int i = tid; i < 768; i += 256) dst[i] = t4[i];
    }
    if (tid < 96) atomicAdd(&bins2[(blockIdx.x & 15) * 96 + tid], lsq[tid]);
}

// ---------------- stage D: 16-row blocks, wave-split K, LDS-tile reduce ----------------
__global__ __launch_bounds__(256) void mconvD_s(
    const float* __restrict__ y2, const float* __restrict__ bins2,  // bins2: [16][96] (48-ch moments)
    const float* __restrict__ g, const float* __restrict__ b,
    const int*   __restrict__ child,  // [N2,8]
    const ush_t* __restrict__ Wb,     // [16][96][32]
    float*       __restrict__ y3,     // [N2,96]
    float*       __restrict__ bins3)  // [16][192]
{
    __shared__ float ssl[96];
    __shared__ float tile[16 * 96];
    const int tid = threadIdx.x;
    for (int i = tid; i < 1536; i += 256) tile[i] = 0.f;
    compute_ss<48, 16>(bins2, g, b, (float)N1, ssl);

    const int lane = tid & 63, wave = tid >> 6;
    const int quad = lane >> 4, l15 = lane & 15;
    const int rowA = blockIdx.x * 16 + l15;

    // 1 vector load instead of 4 scalar loads (8B contiguous)
    const int2 c2 = *(const int2*)(child + (size_t)rowA * 8 + wave * 2);

    f32x4 acc[6] = {};
#pragma unroll
    for (int u = 0; u < 4; ++u) {
        const int ci = wave * 4 + u;
        const int sub = ci & 1;
        const int idx = (u >> 1) ? c2.y : c2.x;
        const int c0 = sub * 32 + quad * 8;
        uint4 au = make_uint4(0, 0, 0, 0);
        if (c0 < 48) {
            const float4 v0 = *(const float4*)(y2 + (size_t)idx * 48 + c0);
            const float4 v1 = *(const float4*)(y2 + (size_t)idx * 48 + c0 + 4);
            const float vv[8] = {v0.x, v0.y, v0.z, v0.w, v1.x, v1.y, v1.z, v1.w};
            unsigned int o4[4];
#pragma unroll
            for (int h = 0; h < 4; ++h) {
                const float a0 = fmaxf(vv[2 * h]     * ssl[c0 + 2 * h]     + ssl[48 + c0 + 2 * h],     0.f);
                const float a1 = fmaxf(vv[2 * h + 1] * ssl[c0 + 2 * h + 1] + ssl[48 + c0 + 2 * h + 1], 0.f);
                o4[h] = (unsigned)f2bf(a0) | ((unsigned)f2bf(a1) << 16);
            }
            au = make_uint4(o4[0], o4[1], o4[2], o4[3]);
        }
        const bf16x8 af = as_bf8(au);
#pragma unroll
        for (int ct = 0; ct < 6; ++ct) {
            const int n = ct * 16 + l15;
            const uint4 bu = *(const uint4*)(Wb + ((size_t)ci * 96 + n) * 32 + quad * 8);
            acc[ct] = __builtin_amdgcn_mfma_f32_16x16x32_bf16(af, as_bf8(bu), acc[ct], 0, 0, 0);
        }
    }

#pragma unroll
    for (int ct = 0; ct < 6; ++ct)
#pragma unroll
        for (int r = 0; r < 4; ++r)
            atomicAdd(&tile[(quad * 4 + r) * 96 + ct * 16 + l15], acc[ct][r]);
    __syncthreads();

    const size_t row0 = (size_t)blockIdx.x * 16;
    for (int i = tid; i < 1536; i += 256) y3[row0 * 96 + i] = tile[i];
    if (tid < 96) {
        float s = 0.f, q = 0.f;
#pragma unroll
        for (int r = 0; r < 16; ++r) { const float v = tile[r * 96 + tid]; s += v; q += v * v; }
        atomicAdd(&bins3[(blockIdx.x & 15) * 192 + tid], s);
        atomicAdd(&bins3[(blockIdx.x & 15) * 192 + 96 + tid], q);
    }
}

// ---------------- stage E: K=27, CIN=96; LDS neigh staging; wave-split chunks ----------------
__global__ __launch_bounds__(256) void mconvE_s(
    const float* __restrict__ y3, const float* __restrict__ bins3,  // bins3: [16][192] (96-ch moments)
    const float* __restrict__ g, const float* __restrict__ b,
    const int*   __restrict__ neigh,  // [N2,27]
    const ush_t* __restrict__ Wb,     // [81][96][32]
    float*       __restrict__ y4,     // [N2,96]
    float*       __restrict__ bins4)  // [16][192]
{
    __shared__ float ssl[192];
    __shared__ float tile[16 * 96];
    __shared__ int   nl[432];
    const int tid = threadIdx.x;
    for (int i = tid; i < 1536; i += 256) tile[i] = 0.f;

    {   // stage neigh slab: 108 uint4
        const uint4* src = (const uint4*)(neigh + (size_t)blockIdx.x * 432);
        uint4* dst = (uint4*)nl;
        for (int i = tid; i < 108; i += 256) dst[i] = src[i];
    }
    compute_ss<96, 16>(bins3, g, b, (float)N2, ssl);   // final sync covers nl staging

    const int lane = tid & 63, wave = tid >> 6;
    const int quad = lane >> 4, l15 = lane & 15;

    const int ci0 = (wave == 0) ? 0 : 21 + (wave - 1) * 20;
    const int cnt = (wave == 0) ? 21 : 20;

    f32x4 acc[6] = {};
    for (int u = 0; u < cnt; ++u) {
        const int ci = ci0 + u;
        const int t = ci / 3, sub = ci % 3;
        const int idx = nl[l15 * 27 + t];
        const int c0 = sub * 32 + quad * 8;
        const float4 v0 = *(const float4*)(y3 + (size_t)idx * 96 + c0);
        const float4 v1 = *(const float4*)(y3 + (size_t)idx * 96 + c0 + 4);
        const float vv[8] = {v0.x, v0.y, v0.z, v0.w, v1.x, v1.y, v1.z, v1.w};
        unsigned int o4[4];
#pragma unroll
        for (int h = 0; h < 4; ++h) {
            const float a0 = fmaxf(vv[2 * h]     * ssl[c0 + 2 * h]     + ssl[96 + c0 + 2 * h],     0.f);
            const float a1 = fmaxf(vv[2 * h + 1] * ssl[c0 + 2 * h + 1] + ssl[96 + c0 + 2 * h + 1], 0.f);
            o4[h] = (unsigned)f2bf(a0) | ((unsigned)f2bf(a1) << 16);
        }
        const bf16x8 af = as_bf8(make_uint4(o4[0], o4[1], o4[2], o4[3]));
#pragma unroll
        for (int ct = 0; ct < 6; ++ct) {
            const int n = ct * 16 + l15;
            const uint4 bu = *(const uint4*)(Wb + ((size_t)ci * 96 + n) * 32 + quad * 8);
            acc[ct] = __builtin_amdgcn_mfma_f32_16x16x32_bf16(af, as_bf8(bu), acc[ct], 0, 0, 0);
        }
    }

#pragma unroll
    for (int ct = 0; ct < 6; ++ct)
#pragma unroll
        for (int r = 0; r < 4; ++r)
            atomicAdd(&tile[(quad * 4 + r) * 96 + ct * 16 + l15], acc[ct][r]);
    __syncthreads();

    const size_t row0 = (size_t)blockIdx.x * 16;
    for (int i = tid; i < 1536; i += 256) y4[row0 * 96 + i] = tile[i];
    if (tid < 96) {
        float s = 0.f, q = 0.f;
#pragma unroll
        for (int r = 0; r < 16; ++r) { const float v = tile[r * 96 + tid]; s += v; q += v * v; }
        atomicAdd(&bins4[(blockIdx.x & 15) * 192 + tid], s);
        atomicAdd(&bins4[(blockIdx.x & 15) * 192 + 96 + tid], q);
    }
}

// ---------------- final write: ss4 in-kernel ----------------
__global__ __launch_bounds__(256) void writeout_s(
    const float* __restrict__ y4, const float* __restrict__ bins4,
    const float* __restrict__ g, const float* __restrict__ b,
    float* __restrict__ out)
{
    __shared__ float ssl[192];
    compute_ss<96, 16>(bins4, g, b, (float)N2, ssl);

    const int i = (blockIdx.x * 256 + threadIdx.x) * 4;   // over N2*96
    const int c = i % 96;
    float4 v = *(const float4*)(y4 + i);
    float4 o;
    o.x = fmaxf(v.x * ssl[c + 0] + ssl[96 + c + 0], 0.f);
    o.y = fmaxf(v.y * ssl[c + 1] + ssl[96 + c + 1], 0.f);
    o.z = fmaxf(v.z * ssl[c + 2] + ssl[96 + c + 2], 0.f);
    o.w = fmaxf(v.w * ssl[c + 3] + ssl[96 + c + 3], 0.f);
    *(float4*)(out + i) = o;
}

// ---------------- host ----------------
extern "C" void kernel_launch(void* const* d_in, const int* in_sizes, int n_in,
                              void* d_out, int out_size, void* d_ws, size_t ws_size,
                              hipStream_t stream)
{
    const float* data   = (const float*)d_in[0];
    const int*   neigh0 = (const int*)d_in[1];
    const int*   child0 = (const int*)d_in[2];
    const int*   neigh1 = (const int*)d_in[3];
    const int*   child1 = (const int*)d_in[4];
    const int*   neigh2 = (const int*)d_in[5];
    const float* w0  = (const float*)d_in[6];
    const float* g0  = (const float*)d_in[7];
    const float* b0  = (const float*)d_in[8];
    const float* wd0 = (const float*)d_in[9];
    const float* gd0 = (const float*)d_in[10];
    const float* bd0 = (const float*)d_in[11];
    const float* w1  = (const float*)d_in[12];
    const float* g1  = (const float*)d_in[13];
    const float* b1  = (const float*)d_in[14];
    const float* wd1 = (const float*)d_in[15];
    const float* gd1 = (const float*)d_in[16];
    const float* bd1 = (const float*)d_in[17];
    const float* wp  = (const float*)d_in[18];
    const float* gp  = (const float*)d_in[19];
    const float* bp  = (const float*)d_in[20];
    float* out = (float*)d_out;

    // bins header (floats) — zeroed by prep_all case 6
    float* wsf = (float*)d_ws;
    float* bins0 = wsf;            // 16*48  = 768
    float* bins1 = wsf + 768;      // 16*96  = 1536
    float* bins2 = wsf + 2304;     // 1536
    float* bins3 = wsf + 3840;     // 16*192 = 3072
    float* bins4 = wsf + 6912;     // 3072 -> 9984, pad to 10240

    // arena
    float* Y2  = wsf + 10240;                        // N1*48 = 1,572,864 f
    float* Y3  = Y2 + (size_t)1572864;               // N2*96 =   393,216 f
    float* Y4  = Y3 + (size_t)393216;                //   393,216 f
    ush_t* Y0B = (ush_t*)(Y4 + (size_t)393216);      // 6,291,456 ush: y0 bf16 [N0,24]
    ush_t* Y1B = Y0B + (size_t)6291456;              // 1,572,864 ush: y1 bf16 [N1,48]
    ush_t* XA  = Y1B + (size_t)1572864;              // 1,048,576 ush: packed input [N0,4]
    ush_t* WB  = XA + (size_t)1048576;               //   524,288 ush: prepped weights

    ush_t* wbA = WB;                 //   4,096
    ush_t* wbB = WB + 4096;          //  12,288
    ush_t* wbC = WB + 16384;         //  64,512 (flattened 42 chunks)
    ush_t* wbD = WB + 80896;         //  49,152
    ush_t* wbE = WB + 130048;        // 248,832 -> end 378,880

    prep_all<<<dim3(1024, 7), 256, 0, stream>>>(w0, wd0, w1, wd1, wp, data,
                                                wbA, wbB, wbC, wbD, wbE, XA, wsf);

    mconvA_s<<<N0 / 128, 256, 0, stream>>>(XA, neigh0, wbA, Y0B, bins0);
    mconvB_s<<<N1 / 64, 256, 0, stream>>>(Y0B, bins0, g0, b0, child0, wbB, Y1B, bins1);
    mconvC_s<<<N1 / 64, 256, 0, stream>>>(Y1B, bins1, gd0, bd0, neigh1, wbC, Y2, bins2);
    mconvD_s<<<N2 / 16, 256, 0, stream>>>(Y2, bins2, g1, b1, child1, wbD, Y3, bins3);
    mconvE_s<<<N2 / 16, 256, 0, stream>>>(Y3, bins3, gd1, bd1, neigh2, wbE, Y4, bins4);
    writeout_s<<<N2 * 96 / 4 / 256, 256, 0, stream>>>(Y4, bins4, gp, bp, out);

    (void)in_sizes; (void)n_in; (void)out_size; (void)ws_size;
}